// Round 1
// baseline (23531.828 us; speedup 1.0000x reference)
//
#include <hip/hip_runtime.h>
#include <cmath>

// ---------------- problem constants ----------------
#define BZ    32
#define NP    196         // patches
#define DDIM  768
#define NHEAD 12
#define MDIM  192         // D/4
#define MH    2304        // MDIM*NHEAD
#define NLAY  6
#define FFDIM 3072
#define HEADU 512
#define NCLS  1000
#define KHEAD 150528      // NP*DDIM
#define BND   4816896     // BZ*NP*DDIM

// ---------------- workspace layout (floats) ----------------
#define OFF_X    0L
#define OFF_B1   4816896L
#define OFF_B2   9633792L
#define OFF_Q    14450688L
#define OFF_K    28901376L
#define OFF_V    43352064L
#define OFF_S    57802752L
#define OFF_T    72554496L
#define OFF_RED  73758720L   // 1024 sums + 1024 sumsq
#define OFF_STAT 73760768L   // mean, inv_std
#define OFF_FEAT 73760772L   // 32*512

__device__ __forceinline__ float gelu_exact(float x){
    return 0.5f * x * (1.0f + erff(x * 0.70710678118654752f));
}

// ---------------- patch extraction ----------------
__global__ void __launch_bounds__(256)
patch_extract_k(const float* __restrict__ img, float* __restrict__ out)
{
    long idx = (long)blockIdx.x * 256 + threadIdx.x;
    if (idx >= (long)BND) return;
    int k = (int)(idx % DDIM);
    long bn = idx / DDIM;
    int n = (int)(bn % NP);
    int b = (int)(bn / NP);
    int c  = k % 3;
    int pj = (k / 3) % 16;
    int pi = k / 48;
    int gi = n / 14, gj = n % 14;
    long src = (((long)(b * 224 + gi * 16 + pi)) * 224 + (gj * 16 + pj)) * 3 + c;
    out[idx] = img[src];
}

// ---------------- global layernorm (3 stages) ----------------
__global__ void __launch_bounds__(256)
reduce_k(const float* __restrict__ x, float* __restrict__ psum, float* __restrict__ psq)
{
    __shared__ float ss[256], sq[256];
    float s = 0.f, q = 0.f;
    const long n4 = BND / 4;
    const float4* x4 = (const float4*)x;
    for (long i = (long)blockIdx.x * 256 + threadIdx.x; i < n4; i += (long)gridDim.x * 256){
        float4 v = x4[i];
        s += v.x + v.y + v.z + v.w;
        q += v.x*v.x + v.y*v.y + v.z*v.z + v.w*v.w;
    }
    ss[threadIdx.x] = s; sq[threadIdx.x] = q;
    __syncthreads();
    for (int st = 128; st > 0; st >>= 1){
        if (threadIdx.x < st){ ss[threadIdx.x] += ss[threadIdx.x+st]; sq[threadIdx.x] += sq[threadIdx.x+st]; }
        __syncthreads();
    }
    if (threadIdx.x == 0){ psum[blockIdx.x] = ss[0]; psq[blockIdx.x] = sq[0]; }
}

__global__ void __launch_bounds__(256)
stats_k(const float* __restrict__ psum, const float* __restrict__ psq, float* __restrict__ stats)
{
    __shared__ float ss[256], sq[256];
    float s = 0.f, q = 0.f;
    for (int i = threadIdx.x; i < 1024; i += 256){ s += psum[i]; q += psq[i]; }
    ss[threadIdx.x] = s; sq[threadIdx.x] = q;
    __syncthreads();
    for (int st = 128; st > 0; st >>= 1){
        if (threadIdx.x < st){ ss[threadIdx.x] += ss[threadIdx.x+st]; sq[threadIdx.x] += sq[threadIdx.x+st]; }
        __syncthreads();
    }
    if (threadIdx.x == 0){
        float mean = ss[0] / (float)BND;
        float var  = sq[0] / (float)BND - mean * mean;
        stats[0] = mean;
        stats[1] = rsqrtf(var + 1e-6f);
    }
}

__global__ void __launch_bounds__(256)
ln_apply_k(const float* __restrict__ x, float* __restrict__ y, const float* __restrict__ stats)
{
    long i = (long)blockIdx.x * 256 + threadIdx.x;  // float4 index
    if (i >= BND / 4) return;
    float mean = stats[0], inv = stats[1];
    float4 v = ((const float4*)x)[i];
    v.x = (v.x - mean) * inv;
    v.y = (v.y - mean) * inv;
    v.z = (v.z - mean) * inv;
    v.w = (v.w - mean) * inv;
    ((float4*)y)[i] = v;
}

// ---------------- softmax over last dim (rows of 196) ----------------
__global__ void __launch_bounds__(64)
softmax_k(float* __restrict__ att)
{
    long row = blockIdx.x;
    float* p = att + row * NP;
    int lane = threadIdx.x;
    float v0 = p[lane];
    float v1 = p[lane + 64];
    float v2 = p[lane + 128];
    float v3 = (lane + 192 < NP) ? p[lane + 192] : -1e30f;
    float m = fmaxf(fmaxf(v0, v1), fmaxf(v2, v3));
    #pragma unroll
    for (int off = 32; off > 0; off >>= 1) m = fmaxf(m, __shfl_xor(m, off));
    v0 = expf(v0 - m); v1 = expf(v1 - m); v2 = expf(v2 - m);
    v3 = (lane + 192 < NP) ? expf(v3 - m) : 0.f;
    float s = v0 + v1 + v2 + v3;
    #pragma unroll
    for (int off = 32; off > 0; off >>= 1) s += __shfl_xor(s, off);
    float inv = 1.0f / s;
    p[lane]       = v0 * inv;
    p[lane + 64]  = v1 * inv;
    p[lane + 128] = v2 * inv;
    if (lane + 192 < NP) p[lane + 192] = v3 * inv;
}

// ---------------- generic strided-batch SGEMM ----------------
// C[i,j] = alpha*sum_k A[i,k]B[k,j]  (+bias1[j]) (+bias2[(i%mod)*ld+j]) (gelu) (+Cadd)
// 64x64 tile, 256 threads, 4x4 micro-tile, BK=16
__global__ void __launch_bounds__(256)
sgemm_k(const float* __restrict__ A, long sAm, long sAk, long sAb, long sAh,
        const float* __restrict__ Bm, long sBk, long sBn, long sBb, long sBh,
        float* __restrict__ C, long sCm, long sCn, long sCb, long sCh,
        const float* __restrict__ Cadd,
        const float* __restrict__ bias1,
        const float* __restrict__ bias2, int b2mod, int b2ld,
        int Md, int Nd, int Kd, int Hdiv, float alpha, int doGelu)
{
    __shared__ float As[16][68];
    __shared__ float Bs[16][68];
    int zb = blockIdx.z / Hdiv, zh = blockIdx.z % Hdiv;
    const float* Ab = A + (long)zb * sAb + (long)zh * sAh;
    const float* Bb = Bm + (long)zb * sBb + (long)zh * sBh;
    float*       Cb = C + (long)zb * sCb + (long)zh * sCh;
    const float* Cab = Cadd ? (Cadd + (long)zb * sCb + (long)zh * sCh) : nullptr;

    int row0 = blockIdx.y * 64, col0 = blockIdx.x * 64;
    int tid = threadIdx.x, tx = tid & 15, ty = tid >> 4;

    float acc[4][4] = {};
    for (int k0 = 0; k0 < Kd; k0 += 16){
        #pragma unroll
        for (int u = 0; u < 4; u++){
            int idx = tid * 4 + u;
            int m = idx >> 4, kk = idx & 15;
            int gm = row0 + m, gk = k0 + kk;
            As[kk][m] = (gm < Md && gk < Kd) ? Ab[(long)gm * sAm + (long)gk * sAk] : 0.f;
        }
        #pragma unroll
        for (int u = 0; u < 4; u++){
            int idx = tid * 4 + u;
            int kk = idx >> 6, n = idx & 63;
            int gn = col0 + n, gk = k0 + kk;
            Bs[kk][n] = (gn < Nd && gk < Kd) ? Bb[(long)gk * sBk + (long)gn * sBn] : 0.f;
        }
        __syncthreads();
        #pragma unroll
        for (int kk = 0; kk < 16; kk++){
            float a0 = As[kk][ty*4+0], a1 = As[kk][ty*4+1], a2 = As[kk][ty*4+2], a3 = As[kk][ty*4+3];
            float b0 = Bs[kk][tx*4+0], b1 = Bs[kk][tx*4+1], b2 = Bs[kk][tx*4+2], b3 = Bs[kk][tx*4+3];
            acc[0][0] += a0*b0; acc[0][1] += a0*b1; acc[0][2] += a0*b2; acc[0][3] += a0*b3;
            acc[1][0] += a1*b0; acc[1][1] += a1*b1; acc[1][2] += a1*b2; acc[1][3] += a1*b3;
            acc[2][0] += a2*b0; acc[2][1] += a2*b1; acc[2][2] += a2*b2; acc[2][3] += a2*b3;
            acc[3][0] += a3*b0; acc[3][1] += a3*b1; acc[3][2] += a3*b2; acc[3][3] += a3*b3;
        }
        __syncthreads();
    }
    #pragma unroll
    for (int i = 0; i < 4; i++){
        int gm = row0 + ty*4 + i;
        if (gm >= Md) continue;
        #pragma unroll
        for (int j = 0; j < 4; j++){
            int gn = col0 + tx*4 + j;
            if (gn >= Nd) continue;
            float v = alpha * acc[i][j];
            if (bias1) v += bias1[gn];
            if (bias2) v += bias2[(long)(gm % b2mod) * b2ld + gn];
            if (doGelu) v = gelu_exact(v);
            long coff = (long)gm * sCm + (long)gn * sCn;
            if (Cab) v += Cab[coff];
            Cb[coff] = v;
        }
    }
}

// ---------------- head: [32 x 150528] @ [150528 x 512], split-K ----------------
__global__ void __launch_bounds__(256)
head_splitk_k(const float* __restrict__ A, const float* __restrict__ W, float* __restrict__ feat)
{
    __shared__ float As[16][36];
    __shared__ float Bs[16][68];
    int col0 = blockIdx.x * 64;
    long kbase = (long)blockIdx.y * 2352;   // 150528/64
    int tid = threadIdx.x, tx = tid & 15, ty = tid >> 4;
    float acc[2][4] = {};
    for (int k0 = 0; k0 < 2352; k0 += 16){
        #pragma unroll
        for (int u = 0; u < 2; u++){
            int idx = tid * 2 + u;
            int m = idx >> 4, kk = idx & 15;
            As[kk][m] = A[(long)m * KHEAD + kbase + k0 + kk];
        }
        #pragma unroll
        for (int u = 0; u < 4; u++){
            int idx = tid * 4 + u;
            int kk = idx >> 6, n = idx & 63;
            Bs[kk][n] = W[(kbase + k0 + kk) * 512 + col0 + n];
        }
        __syncthreads();
        #pragma unroll
        for (int kk = 0; kk < 16; kk++){
            float a0 = As[kk][ty*2], a1 = As[kk][ty*2+1];
            float b0 = Bs[kk][tx*4], b1 = Bs[kk][tx*4+1], b2 = Bs[kk][tx*4+2], b3 = Bs[kk][tx*4+3];
            acc[0][0] += a0*b0; acc[0][1] += a0*b1; acc[0][2] += a0*b2; acc[0][3] += a0*b3;
            acc[1][0] += a1*b0; acc[1][1] += a1*b1; acc[1][2] += a1*b2; acc[1][3] += a1*b3;
        }
        __syncthreads();
    }
    #pragma unroll
    for (int i = 0; i < 2; i++)
        #pragma unroll
        for (int j = 0; j < 4; j++)
            atomicAdd(&feat[(ty*2 + i) * 512 + col0 + tx*4 + j], acc[i][j]);
}

__global__ void __launch_bounds__(256)
head_finish_k(float* __restrict__ feat, const float* __restrict__ hb)
{
    int i = blockIdx.x * 256 + threadIdx.x;
    if (i < BZ * HEADU) feat[i] = gelu_exact(feat[i] + hb[i & 511]);
}

__global__ void __launch_bounds__(256)
cls_k(const float* __restrict__ feat, const float* __restrict__ W,
      const float* __restrict__ bias, float* __restrict__ out)
{
    __shared__ float fs[512];
    int b = blockIdx.y;
    int j = blockIdx.x * 256 + threadIdx.x;
    for (int i = threadIdx.x; i < 512; i += 256) fs[i] = feat[b * 512 + i];
    __syncthreads();
    if (j < NCLS){
        float s = bias[j];
        for (int k = 0; k < 512; k++) s += fs[k] * W[(long)k * NCLS + j];
        out[b * NCLS + j] = s;
    }
}

// ---------------- launch ----------------
extern "C" void kernel_launch(void* const* d_in, const int* in_sizes, int n_in,
                              void* d_out, int out_size, void* d_ws, size_t ws_size,
                              hipStream_t stream)
{
    const float* image   = (const float*)d_in[0];
    const float* patch_w = (const float*)d_in[1];
    const float* patch_b = (const float*)d_in[2];
    const float* pos_emb = (const float*)d_in[3];
    const float* qw  = (const float*)d_in[4];
    const float* qb  = (const float*)d_in[5];
    const float* kw  = (const float*)d_in[6];
    const float* kb  = (const float*)d_in[7];
    const float* vw  = (const float*)d_in[8];
    const float* vb  = (const float*)d_in[9];
    const float* ow1 = (const float*)d_in[10];
    const float* ob1 = (const float*)d_in[11];
    const float* ow2 = (const float*)d_in[12];
    const float* ob2 = (const float*)d_in[13];
    const float* d1w = (const float*)d_in[14];
    const float* d1b = (const float*)d_in[15];
    const float* d2w = (const float*)d_in[16];
    const float* d2b = (const float*)d_in[17];
    const float* head_w = (const float*)d_in[18];
    const float* head_b = (const float*)d_in[19];
    const float* cls_w  = (const float*)d_in[20];
    const float* cls_b  = (const float*)d_in[21];

    float* ws  = (float*)d_ws;
    float* X   = ws + OFF_X;
    float* B1  = ws + OFF_B1;
    float* B2  = ws + OFF_B2;
    float* Q   = ws + OFF_Q;
    float* Kb  = ws + OFF_K;
    float* V   = ws + OFF_V;
    float* S   = ws + OFF_S;
    float* T   = ws + OFF_T;
    float* RSUM = ws + OFF_RED;
    float* RSQ  = ws + OFF_RED + 1024;
    float* STAT = ws + OFF_STAT;
    float* FEAT = ws + OFF_FEAT;
    float* H1  = Kb;             // FFN hidden aliases K..V region (19.3M <= 28.9M floats)
    float* out = (float*)d_out;

    auto gemm = [&](const float* A, long sAm, long sAk, long sAb, long sAh,
                    const float* Bp, long sBk, long sBn, long sBb, long sBh,
                    float* Cp, long sCm, long sCn, long sCb, long sCh,
                    const float* Cadd, const float* b1p, const float* b2p, int b2mod, int b2ld,
                    int Md, int Nd, int Kd, int nbatch, int Hdiv, float alpha, int doGelu){
        dim3 g((Nd + 63) / 64, (Md + 63) / 64, nbatch);
        sgemm_k<<<g, 256, 0, stream>>>(A, sAm, sAk, sAb, sAh, Bp, sBk, sBn, sBb, sBh,
                                       Cp, sCm, sCn, sCb, sCh, Cadd, b1p, b2p, b2mod, b2ld,
                                       Md, Nd, Kd, Hdiv, alpha, doGelu);
    };
    auto layernorm = [&](const float* in, float* outp){
        reduce_k<<<1024, 256, 0, stream>>>(in, RSUM, RSQ);
        stats_k<<<1, 256, 0, stream>>>(RSUM, RSQ, STAT);
        ln_apply_k<<<4704, 256, 0, stream>>>(in, outp, STAT);
    };

    // patch extraction + encoding + positional embedding
    patch_extract_k<<<18816, 256, 0, stream>>>(image, B2);
    gemm(B2, 768, 1, 0, 0,  patch_w, 768, 1, 0, 0,  X, 768, 1, 0, 0,
         nullptr, patch_b, pos_emb, 196, 768,  6272, 768, 768, 1, 1, 1.f, 0);

    const float scale = 1.0f / sqrtf(768.f);
    for (int l = 0; l < NLAY; l++){
        layernorm(X, B1);                                             // x1
        gemm(B1, 768, 1, 0, 0,  qw + (long)l*768*2304, 2304, 1, 0, 0,  Q,  2304, 1, 0, 0,
             nullptr, qb + l*2304, nullptr, 1, 1,  6272, 2304, 768, 1, 1, 1.f, 0);
        gemm(B1, 768, 1, 0, 0,  kw + (long)l*768*2304, 2304, 1, 0, 0,  Kb, 2304, 1, 0, 0,
             nullptr, kb + l*2304, nullptr, 1, 1,  6272, 2304, 768, 1, 1, 1.f, 0);
        gemm(B1, 768, 1, 0, 0,  vw + (long)l*768*2304, 2304, 1, 0, 0,  V,  2304, 1, 0, 0,
             nullptr, vb + l*2304, nullptr, 1, 1,  6272, 2304, 768, 1, 1, 1.f, 0);
        // att[b,h,n,N'] = scale * q.k   (batched over (b,h))
        gemm(Q, 2304, 12, 451584, 1,  Kb, 12, 2304, 451584, 1,  S, 196, 1, 460992, 38416,
             nullptr, nullptr, nullptr, 1, 1,  196, 196, 192, 384, 12, scale, 0);
        softmax_k<<<75264, 64, 0, stream>>>(S);
        // o[b,m,h,n] = sum_N' a[b,h,n,N'] v[b,N',m,h]  -> overwrite Q
        gemm(V, 12, 2304, 451584, 1,  S, 1, 196, 460992, 38416,  Q, 2352, 1, 451584, 196,
             nullptr, nullptr, nullptr, 1, 1,  192, 196, 196, 384, 12, 1.f, 0);
        // t[b,n,m] = (o @ ow1 + ob1)^T   (batched over b)
        gemm(Q, 2352, 1, 451584, 0,  ow1 + (long)l*2352*196, 196, 1, 0, 0,  T, 1, 192, 37632, 0,
             nullptr, nullptr, ob1 + l*192*196, 192, 196,  192, 196, 2352, 32, 1, 1.f, 0);
        // x2 = t @ ow2 + ob2 + x   -> B1
        gemm(T, 192, 1, 0, 0,  ow2 + (long)l*192*768, 768, 1, 0, 0,  B1, 768, 1, 0, 0,
             X, nullptr, ob2 + (long)l*196*768, 196, 768,  6272, 768, 192, 1, 1, 1.f, 0);
        layernorm(B1, B2);                                            // x3
        gemm(B2, 768, 1, 0, 0,  d1w + (long)l*768*3072, 3072, 1, 0, 0,  H1, 3072, 1, 0, 0,
             nullptr, d1b + l*3072, nullptr, 1, 1,  6272, 3072, 768, 1, 1, 1.f, 1);
        gemm(H1, 3072, 1, 0, 0,  d2w + (long)l*3072*768, 768, 1, 0, 0,  X, 768, 1, 0, 0,
             B1, d2b + l*768, nullptr, 1, 1,  6272, 768, 3072, 1, 1, 1.f, 1);
    }
    layernorm(X, B2);
    hipMemsetAsync(FEAT, 0, BZ * HEADU * sizeof(float), stream);
    head_splitk_k<<<dim3(8, 64), 256, 0, stream>>>(B2, head_w, FEAT);
    head_finish_k<<<64, 256, 0, stream>>>(FEAT, head_b);
    cls_k<<<dim3(4, 32), 256, 0, stream>>>(FEAT, cls_w, cls_b, out);
    (void)in_sizes; (void)n_in; (void)out_size; (void)ws_size;
}

// Round 2
// 4869.502 us; speedup vs baseline: 4.8325x; 4.8325x over previous
//
#include <hip/hip_runtime.h>
#include <cmath>

// ---------------- problem constants ----------------
#define BZ    32
#define NP    196
#define DDIM  768
#define NHEAD 12
#define MDIM  192
#define NLAY  6
#define FFDIM 3072
#define HEADU 512
#define NCLS  1000
#define KHEAD 150528      // NP*DDIM
#define BND   4816896     // BZ*NP*DDIM

typedef __bf16 bf16_t;
typedef __bf16 bf16x8 __attribute__((ext_vector_type(8)));
typedef __bf16 bf16x4 __attribute__((ext_vector_type(4)));
typedef float  f32x4  __attribute__((ext_vector_type(4)));

// ---------------- workspace layout (BYTE offsets) ----------------
#define OB_X      0L            // fp32 residual x          19,267,584
#define OB_R      19267584L     // fp32 x2                  19,267,584
#define OB_XB     38535168L     // bf16 LN output            9,633,792
#define OB_SLOTA  48168960L     // S fp32 / Vb bf16 / o bf16 (59,113,472 incl slack)
#define OB_QH     107282432L    // bf16 Q head-major        28,966,912 incl slack
#define OB_KH     136249344L    // bf16 K head-major        28,966,912
#define OB_SLOTB  165216256L    // VT+Pb / H1 / patches     66,879,488
#define OB_PB     198246400L    // = OB_SLOTB + 33,030,144
#define OB_T      232095744L    // bf16 t [6272][192]        2,412,544
#define OB_WQ     234508288L
#define OB_WK     238047232L
#define OB_WV     241586176L
#define OB_WO1    245125120L    // 256x2368 bf16
#define OB_WO2    246337536L
#define OB_WD1    246632448L
#define OB_WD2    251351040L
#define OB_WPAT   256069632L
#define OB_RED    257249280L
#define OB_STAT   257257472L
#define OB_FEAT   257257728L

__device__ __forceinline__ float gelu_exact(float x){
    return 0.5f * x * (1.0f + erff(x * 0.70710678118654752f));
}

__device__ __forceinline__ void gld16(void* g, void* l){
    __builtin_amdgcn_global_load_lds((__attribute__((address_space(1))) void*)g,
                                     (__attribute__((address_space(3))) void*)l, 16, 0, 0);
}

// ---------------- patch extraction (fp32 -> bf16) ----------------
__global__ void __launch_bounds__(256)
patch_extract_k(const float* __restrict__ img, bf16_t* __restrict__ out)
{
    long idx = (long)blockIdx.x * 256 + threadIdx.x;
    if (idx >= (long)BND) return;
    int k = (int)(idx % DDIM);
    long bn = idx / DDIM;
    int n = (int)(bn % NP);
    int b = (int)(bn / NP);
    int c  = k % 3;
    int pj = (k / 3) % 16;
    int pi = k / 48;
    int gi = n / 14, gj = n % 14;
    long src = (((long)(b * 224 + gi * 16 + pi)) * 224 + (gj * 16 + pj)) * 3 + c;
    out[idx] = (bf16_t)img[src];
}

// ---------------- weight convert+transpose fp32->bf16 ----------------
// out[p(c)][j] = (j < IR) ? in[j][c] : 0 ;  p(c)=c or (c%12)*192+c/12
__global__ void __launch_bounds__(256)
wconv_k(const float* __restrict__ in, bf16_t* __restrict__ out,
        int IR, int IC, long OLD, int perm, int padTo)
{
    __shared__ float tile[32][33];
    int tid = threadIdx.x, tx = tid & 31, ty = tid >> 5;
    int c0 = blockIdx.x * 32, r0 = blockIdx.y * 32;
    #pragma unroll
    for (int i = 0; i < 4; i++){
        int r = r0 + ty + 8*i, c = c0 + tx;
        tile[ty + 8*i][tx] = (r < IR && c < IC) ? in[(long)r * IC + c] : 0.f;
    }
    __syncthreads();
    #pragma unroll
    for (int i = 0; i < 4; i++){
        int c = c0 + ty + 8*i, r = r0 + tx;
        if (c < IC && r < padTo){
            long pc = perm ? (long)(c % 12) * 192 + c / 12 : (long)c;
            out[pc * OLD + r] = (bf16_t)tile[tx][ty + 8*i];
        }
    }
}

// ---------------- bf16 V transpose per (h,b) slab: [196][192] -> [192][224] pad0 --------
__global__ void __launch_bounds__(256)
tr_v_k(const bf16_t* __restrict__ in, bf16_t* __restrict__ out)
{
    __shared__ bf16_t tile[32][33];
    int tid = threadIdx.x, tx = tid & 31, ty = tid >> 5;
    int s = blockIdx.z;
    int m0 = blockIdx.x * 32, n0 = blockIdx.y * 32;
    const bf16_t* ib = in + (long)s * (196*192);
    bf16_t* ob = out + (long)s * (192*224);
    #pragma unroll
    for (int i = 0; i < 4; i++){
        int r = n0 + ty + 8*i;           // source row = n'
        tile[ty + 8*i][tx] = (r < 196) ? ib[(long)r * 192 + m0 + tx] : (bf16_t)0.f;
    }
    __syncthreads();
    #pragma unroll
    for (int i = 0; i < 4; i++){
        int m = m0 + ty + 8*i, np_ = n0 + tx;   // m<192 always, np_<224 always
        ob[(long)m * 224 + np_] = tile[tx][ty + 8*i];
    }
}

// ---------------- zero o pad columns [2352,2368) ----------------
__global__ void __launch_bounds__(256)
zero_pad_o_k(bf16_t* __restrict__ o)
{
    int idx = blockIdx.x * 256 + threadIdx.x;
    if (idx >= 32*192*16) return;
    int r = idx >> 4, j = idx & 15;
    o[(long)r * 2368 + 2352 + j] = (bf16_t)0.f;
}

// ---------------- global layernorm ----------------
__global__ void __launch_bounds__(256)
reduce_k(const float* __restrict__ x, float* __restrict__ psum, float* __restrict__ psq)
{
    __shared__ float ss[256], sq[256];
    float s = 0.f, q = 0.f;
    const long n4 = BND / 4;
    const float4* x4 = (const float4*)x;
    for (long i = (long)blockIdx.x * 256 + threadIdx.x; i < n4; i += (long)gridDim.x * 256){
        float4 v = x4[i];
        s += v.x + v.y + v.z + v.w;
        q += v.x*v.x + v.y*v.y + v.z*v.z + v.w*v.w;
    }
    ss[threadIdx.x] = s; sq[threadIdx.x] = q;
    __syncthreads();
    for (int st = 128; st > 0; st >>= 1){
        if (threadIdx.x < st){ ss[threadIdx.x] += ss[threadIdx.x+st]; sq[threadIdx.x] += sq[threadIdx.x+st]; }
        __syncthreads();
    }
    if (threadIdx.x == 0){ psum[blockIdx.x] = ss[0]; psq[blockIdx.x] = sq[0]; }
}

__global__ void __launch_bounds__(256)
stats_k(const float* __restrict__ psum, const float* __restrict__ psq, float* __restrict__ stats)
{
    __shared__ float ss[256], sq[256];
    float s = 0.f, q = 0.f;
    for (int i = threadIdx.x; i < 1024; i += 256){ s += psum[i]; q += psq[i]; }
    ss[threadIdx.x] = s; sq[threadIdx.x] = q;
    __syncthreads();
    for (int st = 128; st > 0; st >>= 1){
        if (threadIdx.x < st){ ss[threadIdx.x] += ss[threadIdx.x+st]; sq[threadIdx.x] += sq[threadIdx.x+st]; }
        __syncthreads();
    }
    if (threadIdx.x == 0){
        float mean = ss[0] / (float)BND;
        float var  = sq[0] / (float)BND - mean * mean;
        stats[0] = mean;
        stats[1] = rsqrtf(var + 1e-6f);
    }
}

__global__ void __launch_bounds__(256)
ln_apply_k(const float* __restrict__ x, bf16_t* __restrict__ yb, float* __restrict__ yf,
           const float* __restrict__ stats)
{
    long i = (long)blockIdx.x * 256 + threadIdx.x;
    if (i >= BND / 4) return;
    float mean = stats[0], inv = stats[1];
    float4 v = ((const float4*)x)[i];
    v.x = (v.x - mean) * inv;
    v.y = (v.y - mean) * inv;
    v.z = (v.z - mean) * inv;
    v.w = (v.w - mean) * inv;
    bf16x4 o4 = { (bf16_t)v.x, (bf16_t)v.y, (bf16_t)v.z, (bf16_t)v.w };
    ((bf16x4*)yb)[i] = o4;
    if (yf) ((float4*)yf)[i] = v;
}

// ---------------- softmax: S fp32 [row][196] -> Pb bf16 [row][224] pad0 ----------------
__global__ void __launch_bounds__(64)
softmax_k(const float* __restrict__ S, bf16_t* __restrict__ P)
{
    long row = blockIdx.x;
    const float* p = S + row * 196;
    bf16_t* q = P + row * 224;
    int lane = threadIdx.x;
    float v0 = p[lane];
    float v1 = p[lane + 64];
    float v2 = p[lane + 128];
    float v3 = (lane + 192 < 196) ? p[lane + 192] : -1e30f;
    float m = fmaxf(fmaxf(v0, v1), fmaxf(v2, v3));
    #pragma unroll
    for (int off = 32; off > 0; off >>= 1) m = fmaxf(m, __shfl_xor(m, off));
    v0 = expf(v0 - m); v1 = expf(v1 - m); v2 = expf(v2 - m);
    v3 = (lane + 192 < 196) ? expf(v3 - m) : 0.f;
    float s = v0 + v1 + v2 + v3;
    #pragma unroll
    for (int off = 32; off > 0; off >>= 1) s += __shfl_xor(s, off);
    float inv = 1.0f / s;
    q[lane]       = (bf16_t)(v0 * inv);
    q[lane + 64]  = (bf16_t)(v1 * inv);
    q[lane + 128] = (bf16_t)(v2 * inv);
    q[lane + 192] = (lane + 192 < 196) ? (bf16_t)(v3 * inv) : (bf16_t)0.f;
}

// ---------------- MFMA bf16 GEMM: 128x128 tile, BK=32, 4 waves ----------------
// Both A and B stored TN (k-contiguous): A[row m][k], B[row n][k].
// modes: 0 f32 rowmajor (+Cadd), 1 bf16 rowmajor, 2 QKV scatter, 3 O scatter, 4 T transpose
__global__ void __launch_bounds__(256)
mfma_gemm_k(const bf16_t* __restrict__ A, long ldA, long sA,
            const bf16_t* __restrict__ B, long ldB, long sB,
            void* __restrict__ C, long ldC, long sC,
            const float* __restrict__ Cadd,
            const float* __restrict__ bias1,
            const float* __restrict__ bias2, int b2mod, int b2ld,
            int Md, int Nd, int Kd, float alpha, int doGelu, int mode)
{
    __shared__ bf16_t sm[2][2][128][32];   // 32 KiB
    const int tid = threadIdx.x;
    const int lane = tid & 63, w = tid >> 6;
    const int wm = w >> 1, wn = w & 1;
    const int z = blockIdx.z;
    const int row0 = blockIdx.y * 128, col0 = blockIdx.x * 128;

    const bf16_t* Ab = A + (long)z * sA + (long)row0 * ldA;
    const bf16_t* Bb = B + (long)z * sB + (long)col0 * ldB;

    f32x4 acc[4][4];
    #pragma unroll
    for (int i = 0; i < 4; i++)
        #pragma unroll
        for (int j = 0; j < 4; j++)
            acc[i][j] = (f32x4){0.f, 0.f, 0.f, 0.f};

    const int fr = lane & 15, kc = lane >> 4;
    const int swz = (fr >> 1) & 3;
    int aOff[4], bOff[4];
    #pragma unroll
    for (int i = 0; i < 4; i++){
        aOff[i] = (wm*64 + i*16 + fr) * 64 + ((kc ^ swz) << 4);
        bOff[i] = (wn*64 + i*16 + fr) * 64 + ((kc ^ swz) << 4);
    }

    auto stage = [&](int buf, int kt){
        long kOff = (long)kt * 32;
        #pragma unroll
        for (int r = 0; r < 2; r++){
            int idx = r*256 + tid;
            int row = idx >> 2, cp = idx & 3;
            int cc = cp ^ ((row >> 1) & 3);
            gld16((void*)(Ab + (long)row*ldA + kOff + cc*8), (void*)&sm[buf][0][row][cp*8]);
            gld16((void*)(Bb + (long)row*ldB + kOff + cc*8), (void*)&sm[buf][1][row][cp*8]);
        }
    };

    const int nt = Kd >> 5;
    stage(0, 0);
    __syncthreads();
    int cur = 0;
    for (int t = 0; t < nt; t++){
        if (t + 1 < nt) stage(cur ^ 1, t + 1);
        const char* baseA = (const char*)sm + cur * 16384;
        const char* baseB = baseA + 8192;
        bf16x8 av[4], bv[4];
        #pragma unroll
        for (int i = 0; i < 4; i++){
            av[i] = *(const bf16x8*)(baseA + aOff[i]);
            bv[i] = *(const bf16x8*)(baseB + bOff[i]);
        }
        #pragma unroll
        for (int i = 0; i < 4; i++)
            #pragma unroll
            for (int j = 0; j < 4; j++)
                acc[i][j] = __builtin_amdgcn_mfma_f32_16x16x32_bf16(av[i], bv[j], acc[i][j], 0, 0, 0);
        __syncthreads();
        cur ^= 1;
    }

    // epilogue: lane holds D[4*kc+r][fr] per 16x16 fragment
    #pragma unroll
    for (int i = 0; i < 4; i++){
        int gmb = row0 + wm*64 + i*16 + kc*4;
        #pragma unroll
        for (int j = 0; j < 4; j++){
            int gn = col0 + wn*64 + j*16 + fr;
            if (gn >= Nd) continue;
            #pragma unroll
            for (int r = 0; r < 4; r++){
                int gm = gmb + r;
                if (gm >= Md) continue;
                float v = alpha * acc[i][j][r];
                if (bias1) v += (mode == 2) ? bias1[(gn % 192)*12 + gn/192] : bias1[gn];
                if (bias2) v += bias2[(long)(gm % b2mod) * b2ld + gn];
                if (doGelu) v = gelu_exact(v);
                if (mode == 0){
                    long off = (long)z*sC + (long)gm*ldC + gn;
                    if (Cadd) v += Cadd[off];
                    ((float*)C)[off] = v;
                } else if (mode == 1){
                    ((bf16_t*)C)[(long)z*sC + (long)gm*ldC + gn] = (bf16_t)v;
                } else if (mode == 2){
                    int h = gn / 192, m = gn % 192, b = gm / 196, n = gm % 196;
                    ((bf16_t*)C)[(((long)h*32 + b)*196 + n)*192 + m] = (bf16_t)v;
                } else if (mode == 3){
                    int h = z / 32, b = z - h*32;
                    ((bf16_t*)C)[((long)(b*192 + gm))*2368 + h*196 + gn] = (bf16_t)v;
                } else {
                    ((bf16_t*)C)[((long)z*196 + gn)*192 + gm] = (bf16_t)v;
                }
            }
        }
    }
}

// ---------------- head: [32 x 150528] @ [150528 x 512] fp32, split-K ----------------
__global__ void __launch_bounds__(256)
head_splitk_k(const float* __restrict__ A, const float* __restrict__ W, float* __restrict__ feat)
{
    __shared__ float As[16][36];
    __shared__ float Bs[16][68];
    int col0 = blockIdx.x * 64;
    long kbase = (long)blockIdx.y * 2352;
    int tid = threadIdx.x, tx = tid & 15, ty = tid >> 4;
    float acc[2][4] = {};
    for (int k0 = 0; k0 < 2352; k0 += 16){
        #pragma unroll
        for (int u = 0; u < 2; u++){
            int idx = tid * 2 + u;
            int m = idx >> 4, kk = idx & 15;
            As[kk][m] = A[(long)m * KHEAD + kbase + k0 + kk];
        }
        #pragma unroll
        for (int u = 0; u < 4; u++){
            int idx = tid * 4 + u;
            int kk = idx >> 6, n = idx & 63;
            Bs[kk][n] = W[(kbase + k0 + kk) * 512 + col0 + n];
        }
        __syncthreads();
        #pragma unroll
        for (int kk = 0; kk < 16; kk++){
            float a0 = As[kk][ty*2], a1 = As[kk][ty*2+1];
            float b0 = Bs[kk][tx*4], b1 = Bs[kk][tx*4+1], b2 = Bs[kk][tx*4+2], b3 = Bs[kk][tx*4+3];
            acc[0][0] += a0*b0; acc[0][1] += a0*b1; acc[0][2] += a0*b2; acc[0][3] += a0*b3;
            acc[1][0] += a1*b0; acc[1][1] += a1*b1; acc[1][2] += a1*b2; acc[1][3] += a1*b3;
        }
        __syncthreads();
    }
    #pragma unroll
    for (int i = 0; i < 2; i++)
        #pragma unroll
        for (int j = 0; j < 4; j++)
            atomicAdd(&feat[(ty*2 + i) * 512 + col0 + tx*4 + j], acc[i][j]);
}

__global__ void __launch_bounds__(256)
head_finish_k(float* __restrict__ feat, const float* __restrict__ hb)
{
    int i = blockIdx.x * 256 + threadIdx.x;
    if (i < BZ * HEADU) feat[i] = gelu_exact(feat[i] + hb[i & 511]);
}

__global__ void __launch_bounds__(256)
cls_k(const float* __restrict__ feat, const float* __restrict__ W,
      const float* __restrict__ bias, float* __restrict__ out)
{
    __shared__ float fs[512];
    int b = blockIdx.y;
    int j = blockIdx.x * 256 + threadIdx.x;
    for (int i = threadIdx.x; i < 512; i += 256) fs[i] = feat[b * 512 + i];
    __syncthreads();
    if (j < NCLS){
        float s = bias[j];
        for (int k = 0; k < 512; k++) s += fs[k] * W[(long)k * NCLS + j];
        out[b * NCLS + j] = s;
    }
}

// ---------------- launch ----------------
extern "C" void kernel_launch(void* const* d_in, const int* in_sizes, int n_in,
                              void* d_out, int out_size, void* d_ws, size_t ws_size,
                              hipStream_t stream)
{
    const float* image   = (const float*)d_in[0];
    const float* patch_w = (const float*)d_in[1];
    const float* patch_b = (const float*)d_in[2];
    const float* pos_emb = (const float*)d_in[3];
    const float* qw  = (const float*)d_in[4];
    const float* qb  = (const float*)d_in[5];
    const float* kw  = (const float*)d_in[6];
    const float* kb  = (const float*)d_in[7];
    const float* vw  = (const float*)d_in[8];
    const float* vb  = (const float*)d_in[9];
    const float* ow1 = (const float*)d_in[10];
    const float* ob1 = (const float*)d_in[11];
    const float* ow2 = (const float*)d_in[12];
    const float* ob2 = (const float*)d_in[13];
    const float* d1w = (const float*)d_in[14];
    const float* d1b = (const float*)d_in[15];
    const float* d2w = (const float*)d_in[16];
    const float* d2b = (const float*)d_in[17];
    const float* head_w = (const float*)d_in[18];
    const float* head_b = (const float*)d_in[19];
    const float* cls_w  = (const float*)d_in[20];
    const float* cls_b  = (const float*)d_in[21];

    char* wsb = (char*)d_ws;
    float*  X    = (float*) (wsb + OB_X);
    float*  R    = (float*) (wsb + OB_R);
    bf16_t* XB   = (bf16_t*)(wsb + OB_XB);
    float*  S    = (float*) (wsb + OB_SLOTA);
    bf16_t* Vb   = (bf16_t*)(wsb + OB_SLOTA);
    bf16_t* O    = (bf16_t*)(wsb + OB_SLOTA);
    bf16_t* Qh   = (bf16_t*)(wsb + OB_QH);
    bf16_t* Kh   = (bf16_t*)(wsb + OB_KH);
    bf16_t* VT   = (bf16_t*)(wsb + OB_SLOTB);
    bf16_t* Pb   = (bf16_t*)(wsb + OB_PB);
    bf16_t* H1   = (bf16_t*)(wsb + OB_SLOTB);
    bf16_t* PATB = (bf16_t*)(wsb + OB_SLOTB);
    bf16_t* Tt   = (bf16_t*)(wsb + OB_T);
    bf16_t* WQ   = (bf16_t*)(wsb + OB_WQ);
    bf16_t* WK   = (bf16_t*)(wsb + OB_WK);
    bf16_t* WV   = (bf16_t*)(wsb + OB_WV);
    bf16_t* WO1  = (bf16_t*)(wsb + OB_WO1);
    bf16_t* WO2  = (bf16_t*)(wsb + OB_WO2);
    bf16_t* WD1  = (bf16_t*)(wsb + OB_WD1);
    bf16_t* WD2  = (bf16_t*)(wsb + OB_WD2);
    bf16_t* WPAT = (bf16_t*)(wsb + OB_WPAT);
    float*  RSUM = (float*) (wsb + OB_RED);
    float*  RSQ  = RSUM + 1024;
    float*  STAT = (float*) (wsb + OB_STAT);
    float*  FEAT = (float*) (wsb + OB_FEAT);
    float*  out  = (float*)d_out;

    auto mg = [&](const bf16_t* A, long ldA, long sA, const bf16_t* B, long ldB, long sB,
                  void* C, long ldC, long sC, const float* Cadd, const float* b1,
                  const float* b2, int b2mod, int b2ld,
                  int Md, int Nd, int Kd, int nb, float alpha, int gelu, int mode){
        dim3 g((Nd + 127) / 128, (Md + 127) / 128, nb);
        mfma_gemm_k<<<g, 256, 0, stream>>>(A, ldA, sA, B, ldB, sB, C, ldC, sC,
                                           Cadd, b1, b2, b2mod, b2ld,
                                           Md, Nd, Kd, alpha, gelu, mode);
    };
    auto wconv = [&](const float* in, bf16_t* o_, int IR, int IC, int perm, long OLD, int padTo){
        dim3 g((IC + 31) / 32, (padTo + 31) / 32);
        wconv_k<<<g, 256, 0, stream>>>(in, o_, IR, IC, OLD, perm, padTo);
    };
    auto layernorm = [&](const float* in, bf16_t* ob, float* of){
        reduce_k<<<1024, 256, 0, stream>>>(in, RSUM, RSQ);
        stats_k<<<1, 256, 0, stream>>>(RSUM, RSQ, STAT);
        ln_apply_k<<<4704, 256, 0, stream>>>(in, ob, of, STAT);
    };

    // ---- patch encode ----
    wconv(patch_w, WPAT, 768, 768, 0, 768, 768);
    patch_extract_k<<<18816, 256, 0, stream>>>(image, PATB);
    mg(PATB, 768, 0, WPAT, 768, 0, X, 768, 0,
       nullptr, patch_b, pos_emb, 196, 768, 6272, 768, 768, 1, 1.f, 0, 0);

    const float scale = 1.0f / sqrtf(768.f);
    for (int l = 0; l < NLAY; l++){
        wconv(qw + (long)l*768*2304, WQ, 768, 2304, 1, 768, 768);
        wconv(kw + (long)l*768*2304, WK, 768, 2304, 1, 768, 768);
        wconv(vw + (long)l*768*2304, WV, 768, 2304, 1, 768, 768);
        wconv(ow1 + (long)l*2352*196, WO1, 2352, 196, 0, 2368, 2368);
        wconv(ow2 + (long)l*192*768, WO2, 192, 768, 0, 192, 192);
        wconv(d1w + (long)l*768*3072, WD1, 768, 3072, 0, 768, 768);
        wconv(d2w + (long)l*3072*768, WD2, 3072, 768, 0, 3072, 3072);

        layernorm(X, XB, nullptr);                                   // x1 (bf16)
        // QKV -> head-major scatter [h][b][n][m]
        mg(XB, 768, 0, WQ, 768, 0, Qh, 0, 0, nullptr, qb + l*2304, nullptr, 1, 1,
           6272, 2304, 768, 1, 1.f, 0, 2);
        mg(XB, 768, 0, WK, 768, 0, Kh, 0, 0, nullptr, kb + l*2304, nullptr, 1, 1,
           6272, 2304, 768, 1, 1.f, 0, 2);
        mg(XB, 768, 0, WV, 768, 0, Vb, 0, 0, nullptr, vb + l*2304, nullptr, 1, 1,
           6272, 2304, 768, 1, 1.f, 0, 2);
        // V^T per slab -> [192][224]
        tr_v_k<<<dim3(6, 7, 384), 256, 0, stream>>>(Vb, VT);
        // S[s][n][n'] = scale * Q . K
        mg(Qh, 192, 37632, Kh, 192, 37632, S, 196, 38416, nullptr, nullptr, nullptr, 1, 1,
           196, 196, 192, 384, scale, 0, 0);
        softmax_k<<<75264, 64, 0, stream>>>(S, Pb);
        // O[m][n] = sum_n' VT[m][n'] P[n][n'] -> scatter o[b][m][h*196+n]
        mg(VT, 224, 43008, Pb, 224, 43904, O, 0, 0, nullptr, nullptr, nullptr, 1, 1,
           192, 196, 224, 384, 1.f, 0, 3);
        zero_pad_o_k<<<384, 256, 0, stream>>>(O);
        // t[b][n][m] = (o_b @ ow1 + ob1)^T  (transpose write)
        mg(O, 2368, 454656, WO1, 2368, 0, Tt, 0, 0, nullptr, nullptr,
           ob1 + (long)l*192*196, 192, 196, 192, 196, 2368, 32, 1.f, 0, 4);
        // x2 = t @ ow2 + ob2 + X -> R (fp32)
        mg(Tt, 192, 0, WO2, 192, 0, R, 768, 0, X, nullptr,
           ob2 + (long)l*196*768, 196, 768, 6272, 768, 192, 1, 1.f, 0, 0);
        layernorm(R, XB, nullptr);                                   // x3 (bf16)
        // FFN1: gelu(x3 @ d1w + d1b) -> H1 bf16
        mg(XB, 768, 0, WD1, 768, 0, H1, 3072, 0, nullptr, d1b + l*3072, nullptr, 1, 1,
           6272, 3072, 768, 1, 1.f, 1, 1);
        // FFN2: gelu(H1 @ d2w + d2b) + R -> X fp32
        mg(H1, 3072, 0, WD2, 3072, 0, X, 768, 0, R, d2b + l*768, nullptr, 1, 1,
           6272, 768, 3072, 1, 1.f, 1, 0);
    }

    layernorm(X, XB, R);                                             // final LN fp32 -> R
    hipMemsetAsync(FEAT, 0, BZ * HEADU * sizeof(float), stream);
    head_splitk_k<<<dim3(8, 64), 256, 0, stream>>>(R, head_w, FEAT);
    head_finish_k<<<64, 256, 0, stream>>>(FEAT, head_b);
    cls_k<<<dim3(4, 32), 256, 0, stream>>>(FEAT, cls_w, cls_b, out);
    (void)in_sizes; (void)n_in; (void)out_size; (void)ws_size;
}